// Round 4
// baseline (736.269 us; speedup 1.0000x reference)
//
#include <hip/hip_runtime.h>
#include <cstdint>

namespace {
constexpr int B = 16, C = 256, N = 16384, K = 64;
constexpr float TEMP = 20.0f, EPS = 1e-6f;
// zT row stride in halfwords: 528 B/row, 16B-aligned, spreads b128 reads.
constexpr int ZRS = 264;
constexpr int CCH = 32;            // c per phase-1 chunk
constexpr int NCHUNK = C / CCH;    // 8
// phase-1 LDS (u32 units): xT hi/lo [256 n][16 u32], mT hi/lo [64 k][16 u32].
constexpr int XTH = 0, XTL = 4096, MTH = 8192, MTL = 9216;
constexpr int SMU_SIZE = 10240;    // 40 KB (phase 2 zT = 33 KB fits at offset 0)
}

typedef _Float16 f16x8 __attribute__((ext_vector_type(8)));
typedef float f32x4 __attribute__((ext_vector_type(4)));

__device__ __forceinline__ uint32_t pack2(_Float16 a, _Float16 b) {
  union { _Float16 h[2]; uint32_t u; } t;
  t.h[0] = a; t.h[1] = b;
  return t.u;
}

__device__ __forceinline__ void hilo(float v0, float v1, uint32_t& hp, uint32_t& lp) {
  const _Float16 h0 = (_Float16)v0, h1 = (_Float16)v1;
  const _Float16 l0 = (_Float16)(v0 - (float)h0);
  const _Float16 l1 = (_Float16)(v1 - (float)h1);
  hp = pack2(h0, h1);
  lp = pack2(l0, l1);
}

// Slot-swizzled u32 index into a row-major [rows][16 u32] LDS tile.
// slot (16B unit) ^= (row>>1)&3: b128 writes and b128 fragment reads both land
// lanes spread over all bank groups -> near-conflict-free.
__device__ __forceinline__ int swz(int row, int slot) {
  return row * 16 + 4 * (slot ^ ((row >> 1) & 3));
}

// Raw barrier: drains LDS (lgkmcnt) only. Global->register loads STAY IN
// FLIGHT across it (unlike __syncthreads, which drains vmcnt(0) too). This is
// the T3/T4 counted-vmcnt mechanism in plain HIP: the consumer-side vmcnt
// waits are compiler-inserted at first register use, fine-grained.
#define BAR()                                              \
  do {                                                     \
    asm volatile("s_waitcnt lgkmcnt(0)" ::: "memory");     \
    __builtin_amdgcn_s_barrier();                          \
  } while (0)

// Fused EM step. Block = 256 n's of one batch, 4 waves.
// Phase 1 (MFMA): Z[256n][64k] = xT[256n][256c] . m[256c][64k], c chunked by 32,
//   x/m split fp16 hi+lo (hh+hl+lh MFMAs) -> ~fp32-accurate scores.
//   2-DEEP PIPELINE: chunks ci+1, ci+2 loads outstanding while packing ci.
//   Raw barriers (no vmcnt drain) + sched_barrier(0) pin the load issue slot.
//   x loads are float2 (16/chunk/thread): thread (tt=tid&127, ch=tid>>7) owns
//   rows n={2tt,2tt+1}, c-half ch -> slots {2ch,2ch+1}.
// Softmax in MFMA D-layout (4 regs x 16 lr-lanes per row, shfl_xor reduce).
// FINAL: scatter-store fp32 out, done.
// Phase 2 (MFMA): zT fp16 in LDS (b64-packed writes), S col-sums,
//   m'[c][k] += x[c][n].z[n][k] with ks-loop register prefetch, atomics to mt.
template <bool FINAL>
__global__ __launch_bounds__(256, 2) void kstep_kernel(
    const float* __restrict__ x,   // [B][C][N] fp32
    const float* __restrict__ m,   // [B][C][K] fp32 (or mu with mstride=0)
    const int mstride,             // 0 (step 0: mu broadcast) or C*K
    float* __restrict__ mt,        // [B][C][K] accum (pre-zeroed)
    float* __restrict__ S,         // [B][K] accum (pre-zeroed)
    float* __restrict__ out) {     // [B][N][K] fp32
  __shared__ __attribute__((aligned(16))) uint32_t smu[SMU_SIZE];
  const int tid = threadIdx.x;
  const int b = blockIdx.y;
  const int n0 = blockIdx.x * 256;
  const int w = tid >> 6;
  const int lane = tid & 63;
  const int lr = lane & 15, lh = lane >> 4;
  const int tt = tid & 127, ch = tid >> 7;

  // ---- phase 1: scores via MFMA, 2-deep reg-prefetch pipeline ----
  f32x4 acc[4][4];
#pragma unroll
  for (int mi = 0; mi < 4; ++mi)
#pragma unroll
    for (int ni = 0; ni < 4; ++ni) acc[mi][ni] = (f32x4){0.f, 0.f, 0.f, 0.f};

  const float2* xcol2 = (const float2*)(x + (size_t)b * C * N + n0);
  const float* mrow = m + (size_t)b * mstride + lane;    // k = lane

  float2 xa[16], xb[16];
  float ma[8], mb[8];

#define LOADX(XV, CI)                                                     \
  {                                                                       \
    const int cc = (CI) * CCH + 16 * ch;                                  \
    _Pragma("unroll") for (int j = 0; j < 16; ++j)                        \
        XV[j] = xcol2[(size_t)(cc + j) * (N / 2) + tt];                   \
  }
#define LOADM(MV, CI)                                                     \
  {                                                                       \
    const int cc = (CI) * CCH + 8 * w;                                    \
    _Pragma("unroll") for (int j = 0; j < 8; ++j)                         \
        MV[j] = mrow[(size_t)(cc + j) * K];                               \
  }

#define PACK(XV, MV)                                                         \
  {                                                                          \
    _Pragma("unroll") for (int p = 0; p < 2; ++p) {                          \
      _Pragma("unroll") for (int sl = 0; sl < 2; ++sl) {                     \
        uint32_t hp[4], lp[4];                                               \
        _Pragma("unroll") for (int jj = 0; jj < 4; ++jj) {                   \
          const float v0 = p ? XV[8 * sl + 2 * jj].y : XV[8 * sl + 2 * jj].x;\
          const float v1 =                                                   \
              p ? XV[8 * sl + 2 * jj + 1].y : XV[8 * sl + 2 * jj + 1].x;     \
          hilo(v0, v1, hp[jj], lp[jj]);                                      \
        }                                                                    \
        const int e = swz(2 * tt + p, 2 * ch + sl);                          \
        *(uint4*)&smu[XTH + e] = make_uint4(hp[0], hp[1], hp[2], hp[3]);     \
        *(uint4*)&smu[XTL + e] = make_uint4(lp[0], lp[1], lp[2], lp[3]);     \
      }                                                                      \
    }                                                                        \
    {                                                                        \
      uint32_t hp[4], lp[4];                                                 \
      _Pragma("unroll") for (int jj = 0; jj < 4; ++jj)                       \
          hilo(MV[2 * jj], MV[2 * jj + 1], hp[jj], lp[jj]);                  \
      const int e = swz(lane, w);                                            \
      *(uint4*)&smu[MTH + e] = make_uint4(hp[0], hp[1], hp[2], hp[3]);       \
      *(uint4*)&smu[MTL + e] = make_uint4(lp[0], lp[1], lp[2], lp[3]);       \
    }                                                                        \
  }

#define FRAGMFMA()                                                           \
  {                                                                          \
    f16x8 ah[4], al[4];                                                      \
    _Pragma("unroll") for (int t = 0; t < 4; ++t) {                          \
      const int ea = swz(w * 64 + t * 16 + lr, lh);                          \
      ah[t] = *(const f16x8*)&smu[XTH + ea];                                 \
      al[t] = *(const f16x8*)&smu[XTL + ea];                                 \
    }                                                                        \
    _Pragma("unroll") for (int ni = 0; ni < 4; ++ni) {                       \
      const int eb = swz(ni * 16 + lr, lh);                                  \
      const f16x8 bh = *(const f16x8*)&smu[MTH + eb];                        \
      const f16x8 bl = *(const f16x8*)&smu[MTL + eb];                        \
      _Pragma("unroll") for (int mi = 0; mi < 4; ++mi) {                     \
        acc[mi][ni] = __builtin_amdgcn_mfma_f32_16x16x32_f16(                \
            ah[mi], bh, acc[mi][ni], 0, 0, 0);                               \
        acc[mi][ni] = __builtin_amdgcn_mfma_f32_16x16x32_f16(                \
            ah[mi], bl, acc[mi][ni], 0, 0, 0);                               \
        acc[mi][ni] = __builtin_amdgcn_mfma_f32_16x16x32_f16(                \
            al[mi], bh, acc[mi][ni], 0, 0, 0);                               \
      }                                                                      \
    }                                                                        \
  }

// One chunk: guard-barrier, pack (compiler inserts counted vmcnt wait for this
// buffer's loads), publish-barrier, issue chunk CI+2 into the same buffer,
// sched_barrier(0) pins the loads BEFORE the MFMA cluster, then frags+MFMA.
#define STEP(XV, MV, CI)                        \
  {                                             \
    BAR();                                      \
    PACK(XV, MV);                               \
    BAR();                                      \
    if ((CI) + 2 < NCHUNK) {                    \
      LOADX(XV, (CI) + 2);                      \
      LOADM(MV, (CI) + 2);                      \
    }                                           \
    __builtin_amdgcn_sched_barrier(0);          \
    FRAGMFMA();                                 \
  }

  LOADX(xa, 0); LOADM(ma, 0);
  LOADX(xb, 1); LOADM(mb, 1);
  STEP(xa, ma, 0); STEP(xb, mb, 1);
  STEP(xa, ma, 2); STEP(xb, mb, 3);
  STEP(xa, ma, 4); STEP(xb, mb, 5);
  STEP(xa, ma, 6); STEP(xb, mb, 7);

#undef STEP
#undef FRAGMFMA
#undef PACK
#undef LOADM
#undef LOADX

  // ---- softmax over k, in D-layout ----
  const float sc = FINAL ? 1.0f : TEMP;  // final einsum has NO temperature
#pragma unroll
  for (int mi = 0; mi < 4; ++mi)
#pragma unroll
    for (int r = 0; r < 4; ++r) {
      float v0 = acc[mi][0][r] * sc, v1 = acc[mi][1][r] * sc;
      float v2 = acc[mi][2][r] * sc, v3 = acc[mi][3][r] * sc;
      float mx = fmaxf(fmaxf(v0, v1), fmaxf(v2, v3));
      mx = fmaxf(mx, __shfl_xor(mx, 1));
      mx = fmaxf(mx, __shfl_xor(mx, 2));
      mx = fmaxf(mx, __shfl_xor(mx, 4));
      mx = fmaxf(mx, __shfl_xor(mx, 8));
      v0 = __expf(v0 - mx); v1 = __expf(v1 - mx);
      v2 = __expf(v2 - mx); v3 = __expf(v3 - mx);
      float s = v0 + v1 + v2 + v3;
      s += __shfl_xor(s, 1);
      s += __shfl_xor(s, 2);
      s += __shfl_xor(s, 4);
      s += __shfl_xor(s, 8);
      const float inv = 1.0f / s;
      acc[mi][0][r] = v0 * inv; acc[mi][1][r] = v1 * inv;
      acc[mi][2][r] = v2 * inv; acc[mi][3][r] = v3 * inv;
    }

  if (FINAL) {
    float* ob = out + ((size_t)b * N + n0 + w * 64) * K;
#pragma unroll
    for (int mi = 0; mi < 4; ++mi)
#pragma unroll
      for (int r = 0; r < 4; ++r) {
        const int row = mi * 16 + lh * 4 + r;
#pragma unroll
        for (int ni = 0; ni < 4; ++ni)
          ob[(size_t)row * K + ni * 16 + lr] = acc[mi][ni][r];
      }
    return;
  }

  // ---- phase 2 ----
  __syncthreads();  // full drain OK at phase boundary (once)
  _Float16* zt = (_Float16*)smu;  // zT fp16 [k=64][n=256], row stride ZRS
#pragma unroll
  for (int mi = 0; mi < 4; ++mi)
#pragma unroll
    for (int ni = 0; ni < 4; ++ni) {
      // 4 contiguous n (r=0..3) at row k -> one b64 write
      const uint32_t w0 = pack2((_Float16)acc[mi][ni][0], (_Float16)acc[mi][ni][1]);
      const uint32_t w1 = pack2((_Float16)acc[mi][ni][2], (_Float16)acc[mi][ni][3]);
      *(uint2*)&zt[(ni * 16 + lr) * ZRS + w * 64 + mi * 16 + lh * 4] =
          make_uint2(w0, w1);
    }
  __syncthreads();

  // prefetch ks=0's x rows now (overlaps the S-sum below)
  const int cbase = w * 64;
  const float* xw = x + (size_t)b * C * N + n0;
  float4 cu[4], cv[4];
#define LOAD_KS(ks)                                                         \
  {                                                                         \
    const int np = (ks) * 32 + lh * 8;                                      \
    _Pragma("unroll") for (int mi = 0; mi < 4; ++mi) {                      \
      const float* p = xw + (size_t)(cbase + mi * 16 + lr) * N + np;        \
      cu[mi] = *(const float4*)p;                                           \
      cv[mi] = *(const float4*)(p + 4);                                     \
    }                                                                       \
  }
  LOAD_KS(0);

  {  // S[b,k] += sum over this block's n of z; thread = (k, n-quarter)
    const int k = tid & 63, qt = tid >> 6;
    float s = 0.f;
#pragma unroll
    for (int j = 0; j < 8; ++j) {
      f16x8 v = *(const f16x8*)(zt + k * ZRS + qt * 64 + j * 8);
#pragma unroll
      for (int e = 0; e < 8; ++e) s += (float)v[e];
    }
    atomicAdd(&S[b * K + k], s);
  }

  // MFMA: m'[c][k] += sum_n x[c][n] * z[n][k]; wave w owns c in [cbase, cbase+64)
  f32x4 acc2[4][4];
#pragma unroll
  for (int mi = 0; mi < 4; ++mi)
#pragma unroll
    for (int ni = 0; ni < 4; ++ni) acc2[mi][ni] = (f32x4){0.f, 0.f, 0.f, 0.f};

  for (int ks = 0; ks < 8; ++ks) {
    const int np = ks * 32 + lh * 8;
    f16x8 af[4];
#pragma unroll
    for (int mi = 0; mi < 4; ++mi) {
      f16x8 t;
      t[0] = (_Float16)cu[mi].x; t[1] = (_Float16)cu[mi].y;
      t[2] = (_Float16)cu[mi].z; t[3] = (_Float16)cu[mi].w;
      t[4] = (_Float16)cv[mi].x; t[5] = (_Float16)cv[mi].y;
      t[6] = (_Float16)cv[mi].z; t[7] = (_Float16)cv[mi].w;
      af[mi] = t;
    }
    if (ks + 1 < 8) LOAD_KS(ks + 1);  // in flight under the 16 MFMAs
#pragma unroll
    for (int ni = 0; ni < 4; ++ni) {
      const f16x8 bf = *(const f16x8*)(zt + (ni * 16 + lr) * ZRS + np);
#pragma unroll
      for (int mi = 0; mi < 4; ++mi)
        acc2[mi][ni] =
            __builtin_amdgcn_mfma_f32_16x16x32_f16(af[mi], bf, acc2[mi][ni], 0, 0, 0);
    }
  }
#undef LOAD_KS

  // D layout (16x16): col = lane&15 (k), row = (lane>>4)*4 + reg (c).
#pragma unroll
  for (int mi = 0; mi < 4; ++mi)
#pragma unroll
    for (int ni = 0; ni < 4; ++ni) {
      const int k = ni * 16 + lr;
#pragma unroll
      for (int r = 0; r < 4; ++r) {
        const int c = cbase + mi * 16 + lh * 4 + r;
        atomicAdd(&mt[((size_t)b * C + c) * K + k], acc2[mi][ni][r]);
      }
    }
}

// m[b,c,k] = l2norm_c( mt[b,:,k] * l1scale[k] );  l1scale = 1/(EPS + S[b,k])
// Also re-zeroes mt and S for the next EM step (saves the kzero launch).
__global__ __launch_bounds__(64) void kl2_kernel(float* __restrict__ mt,
                                                 float* __restrict__ S,
                                                 float* __restrict__ m) {
  const int k = blockIdx.x, b = blockIdx.y, lane = threadIdx.x;
  const float s = 1.0f / (EPS + S[b * K + k]);
  float v[4];
  float ss = 0.f;
#pragma unroll
  for (int i = 0; i < 4; ++i) {
    const size_t idx = ((size_t)b * C + lane + 64 * i) * K + k;
    v[i] = mt[idx] * s;
    mt[idx] = 0.f;  // re-zero for next step's atomics
    ss += v[i] * v[i];
  }
  if (lane == 0) S[b * K + k] = 0.f;
#pragma unroll
  for (int off = 32; off >= 1; off >>= 1) ss += __shfl_xor(ss, off);
  const float inv = 1.0f / (EPS + sqrtf(ss));
#pragma unroll
  for (int i = 0; i < 4; ++i)
    m[((size_t)b * C + lane + 64 * i) * K + k] = v[i] * inv;
}

__global__ __launch_bounds__(256) void kzero_kernel(float* __restrict__ p, int ntot) {
  const int i = blockIdx.x * 256 + threadIdx.x;
  if (i < ntot) p[i] = 0.f;
}

extern "C" void kernel_launch(void* const* d_in, const int* in_sizes, int n_in,
                              void* d_out, int out_size, void* d_ws,
                              size_t ws_size, hipStream_t stream) {
  const float* x = (const float*)d_in[0];   // fp32 [B][C][N]
  const float* mu = (const float*)d_in[1];  // fp32 [1][C][K]
  float* out = (float*)d_out;               // fp32 [B][N][K]

  // ws layout (fp32): m[B*C*K] | mt[B*C*K] | S[B*K]  (~2.01 MB total)
  float* m = (float*)d_ws;
  float* mt = m + (size_t)B * C * K;
  float* S = mt + (size_t)B * C * K;
  const int nz = B * C * K + B * K;  // mt + S contiguous

  kzero_kernel<<<(nz + 255) / 256, 256, 0, stream>>>(mt, nz);
  for (int step = 0; step < 3; ++step) {
    // step 0 reads mu directly (broadcast over b via mstride=0) - no kinit.
    const float* msrc = step == 0 ? mu : m;
    const int mstride = step == 0 ? 0 : C * K;
    kstep_kernel<false><<<dim3(N / 256, B), 256, 0, stream>>>(x, msrc, mstride,
                                                              mt, S, nullptr);
    kl2_kernel<<<dim3(K, B), 64, 0, stream>>>(mt, S, m);  // + re-zero mt,S
  }
  kstep_kernel<true><<<dim3(N / 256, B), 256, 0, stream>>>(x, m, C * K, nullptr,
                                                           nullptr, out);
}